// Round 8
// baseline (194.821 us; speedup 1.0000x reference)
//
#include <hip/hip_runtime.h>
#include <math.h>

#define NN 50000
#define NE 800000
#define D  128
#define SCAN_CHUNK 1024
#define NSCAN 49          // ceil(NN/SCAN_CHUNK)
#define PG_BLOCKS 782     // ceil((NE/4)/256)
#define NROLES 1564       // 782 count + 782 gemm
#define SS_BLOCKS 832     // 49 scan + 783 scale (783*256 = 200448 >= NN*4)

typedef __attribute__((ext_vector_type(8))) short bf16x8;
typedef __attribute__((ext_vector_type(4))) float f32x4;

__device__ __forceinline__ unsigned short f32_to_bf16(float f) {
    unsigned u = __float_as_uint(f);
    u = u + 0x7FFFu + ((u >> 16) & 1u);   // RNE
    return (unsigned short)(u >> 16);
}

// fast tanh: 1 - 2*rcp(e^{2x}+1). Exact at saturation. |err| ~1e-6.
__device__ __forceinline__ float fast_tanh(float x) {
    float e = __expf(2.0f * x);
    return fmaf(-2.0f, __builtin_amdgcn_rcpf(e + 1.0f), 1.0f);
}

// ---- K0: deg/flag zero; W bf16-frag pack (block 0); zb sentinel row --------
__global__ __launch_bounds__(256) void k_init(
        const float* __restrict__ Wg, int* __restrict__ deg,
        int* __restrict__ flag, unsigned short* __restrict__ wpk,
        unsigned short* __restrict__ zb) {
    int tid = threadIdx.x;
    int idx = blockIdx.x * 256 + tid;

    if (idx < NN / 4) ((int4*)deg)[idx] = (int4){0, 0, 0, 0};
    if (idx == NN / 4) *flag = 0;

    if (blockIdx.x == 0) {
        // frag = nt*256 + kt*64 + quad*16 + lo, elem j = k&7 (verified layout)
#pragma unroll 8
        for (int i = 0; i < 64; i++) {
            int o = i * 256 + tid;
            int j = o & 7, frag = o >> 3;
            int lo = frag & 15, quad = (frag >> 4) & 3;
            int kt = (frag >> 6) & 3, nt = frag >> 8;
            wpk[o] = f32_to_bf16(Wg[(kt * 32 + quad * 8 + j) * 128 + nt * 16 + lo]);
        }
    }
    if (blockIdx.x == 1 && tid < 64)
        ((unsigned*)(zb + (size_t)NN * D))[tid] = 0u;   // sentinel row = 0
}

// ---- K1: count-atomics blocks + GEMM blocks interleaved by parity.
// GEMM writes UNSCALED fp32 zf (no dinv dep) -> overlaps with atomics. ------
__global__ __launch_bounds__(256) void k_count_gemm(
        const float* __restrict__ h, const uint4* __restrict__ wpk4,
        const int* __restrict__ ei, int* __restrict__ deg,
        unsigned short* __restrict__ rank, float* __restrict__ zf,
        int* __restrict__ outtail, int tailN) {
    int tid = threadIdx.x;
    int bid = blockIdx.x;

    if (bid & 1) {
        int g = (bid >> 1) * 256 + tid;
        if (g < NE / 4) {
            int4 d4 = ((const int4*)(ei + NE))[g];
            ushort4 r;
            r.x = (unsigned short)atomicAdd(&deg[d4.x], 1);
            r.y = (unsigned short)atomicAdd(&deg[d4.y], 1);
            r.z = (unsigned short)atomicAdd(&deg[d4.z], 1);
            r.w = (unsigned short)atomicAdd(&deg[d4.w], 1);
            ((ushort4*)rank)[g] = r;
        }
        for (int i = g; i < tailN; i += PG_BLOCKS * 256) outtail[i] = 0;
        return;
    }

    int gid = bid >> 1;
    int w = tid >> 6, lane = tid & 63;
    int quad = lane >> 4, lo = lane & 15;
    int rowBase = gid * 64 + w * 16;
    int rowA = rowBase + lo; if (rowA > NN - 1) rowA = NN - 1;
    const float4* h4 = (const float4*)h;

    bf16x8 af[4];
#pragma unroll
    for (int kt = 0; kt < 4; kt++) {
        float4 u = h4[(size_t)rowA * 32 + kt * 8 + quad * 2];
        float4 v = h4[(size_t)rowA * 32 + kt * 8 + quad * 2 + 1];
        bf16x8 a;
        a[0] = (short)f32_to_bf16(u.x); a[1] = (short)f32_to_bf16(u.y);
        a[2] = (short)f32_to_bf16(u.z); a[3] = (short)f32_to_bf16(u.w);
        a[4] = (short)f32_to_bf16(v.x); a[5] = (short)f32_to_bf16(v.y);
        a[6] = (short)f32_to_bf16(v.z); a[7] = (short)f32_to_bf16(v.w);
        af[kt] = a;
    }

    f32x4 acc[8];
#pragma unroll
    for (int nt = 0; nt < 8; nt++) acc[nt] = (f32x4){0.f, 0.f, 0.f, 0.f};

#pragma unroll
    for (int kt = 0; kt < 4; kt++)
#pragma unroll
        for (int nt = 0; nt < 8; nt++) {
            uint4 tb = wpk4[nt * 256 + kt * 64 + lane];   // coalesced, L1-hit
            acc[nt] = __builtin_amdgcn_mfma_f32_16x16x32_bf16(
                af[kt], __builtin_bit_cast(bf16x8, tb), acc[nt], 0, 0, 0);
        }

#pragma unroll
    for (int reg = 0; reg < 4; reg++) {
        int row = rowBase + quad * 4 + reg;
        if (row < NN) {
#pragma unroll
            for (int nt = 0; nt < 8; nt++)
                zf[(size_t)row * D + nt * 16 + lo] = acc[nt][reg];
        }
    }
}

// ---- K2: scan(blocks 0-48) || zb-scale(blocks 49+). NO cross-block deps:
// scale recomputes dinv inline from deg (bit-identical). Kernel boundary
// (not an in-kernel barrier) publishes rowoff to K3 — round-5 lesson. -------
__global__ __launch_bounds__(256) void k_scan_scale(
        const int* __restrict__ deg, int* __restrict__ partial,
        int* __restrict__ flag, int* __restrict__ rowoff,
        float* __restrict__ dinv, const float* __restrict__ zf,
        unsigned short* __restrict__ zb) {
    __shared__ int wsum[4];
    int tid = threadIdx.x;
    int bid = blockIdx.x;

    if (bid < NSCAN) {
        // ---------------- scan role (proven structure) ----------------
        int lane = tid & 63, wv = tid >> 6;
        int base = bid * SCAN_CHUNK + tid * 4;
        int d[4]; int s = 0;
#pragma unroll
        for (int j = 0; j < 4; j++) {
            int i = base + j;
            d[j] = 0;
            if (i < NN) {
                d[j] = deg[i];
                s += d[j];
                dinv[i] = rsqrtf((float)d[j] + 1.0f);   // +1 self loop
            }
        }
        int v = s;
#pragma unroll
        for (int off = 1; off < 64; off <<= 1) {
            int u = __shfl_up(v, off, 64);
            if (lane >= off) v += u;
        }
        if (lane == 63) wsum[wv] = v;
        __syncthreads();
        int add = 0;
#pragma unroll
        for (int k = 0; k < 4; k++) if (k < wv) add += wsum[k];
        int inc = v + add;
        if (tid == 255) {
            atomicExch(&partial[bid], inc);
            __threadfence();
            atomicAdd(flag, 1);
            while (atomicAdd(flag, 0) < NSCAN) {}   // 49 spinners, co-resident
        }
        __syncthreads();
        int pv = (lane < NSCAN && lane < bid) ? atomicAdd(&partial[lane], 0) : 0;
#pragma unroll
        for (int off = 32; off > 0; off >>= 1) pv += __shfl_xor(pv, off, 64);
        int ex = inc - s + pv;
#pragma unroll
        for (int j = 0; j < 4; j++) {
            int i = base + j;
            if (i < NN) {
                rowoff[i] = ex;
                ex += d[j];
                if (i == NN - 1) rowoff[NN] = ex;   // sentinel = NE
            }
        }
    } else {
        // ------- scale role: zb = bf16(zf * rsqrt(deg+1)), bit-identical ----
        int g = (bid - NSCAN) * 256 + tid;
        if (g < NN * 4) {
            int row = g >> 2, seg = g & 3;
            float dn = rsqrtf((float)deg[row] + 1.0f);
            const float4* src = (const float4*)(zf + (size_t)row * D + seg * 32);
            uint4* dst = (uint4*)(zb + (size_t)row * D + seg * 32);
#pragma unroll
            for (int i = 0; i < 4; i++) {
                float4 a = src[i * 2], bb = src[i * 2 + 1];
                uint4 o;
                o.x = (unsigned)f32_to_bf16(a.x * dn) | ((unsigned)f32_to_bf16(a.y * dn) << 16);
                o.y = (unsigned)f32_to_bf16(a.z * dn) | ((unsigned)f32_to_bf16(a.w * dn) << 16);
                o.z = (unsigned)f32_to_bf16(bb.x * dn) | ((unsigned)f32_to_bf16(bb.y * dn) << 16);
                o.w = (unsigned)f32_to_bf16(bb.z * dn) | ((unsigned)f32_to_bf16(bb.w * dn) << 16);
                dst[i] = o;
            }
        }
    }
}

// ---- K3: CSR fill, plain cached loads (kernel boundary = coherence) -------
__global__ __launch_bounds__(320) void k_fill(const int* __restrict__ ei,
                                              const int* __restrict__ rowoff,
                                              const unsigned short* __restrict__ rank,
                                              int* __restrict__ csr) {
    int t = blockIdx.x * 320 + threadIdx.x;   // 625*320*4 = NE exactly
    int4 s4 = ((const int4*)ei)[t];
    int4 d4 = ((const int4*)(ei + NE))[t];
    ushort4 r4 = ((const ushort4*)rank)[t];
    csr[rowoff[d4.x] + r4.x] = s4.x;
    csr[rowoff[d4.y] + r4.y] = s4.y;
    csr[rowoff[d4.z] + r4.z] = s4.z;
    csr[rowoff[d4.w] + r4.w] = s4.w;
}

// ---- K4: gather + LN + tanh. Round-6 skeleton; ONE delta: pairwise row
// interleave (rows 0+1, 2+3) with named pa/pb arrays -> 32 loads in flight
// (~64 VGPR target). Per-row summation order unchanged -> bit-identical. ----
__global__ __launch_bounds__(256) void k_gather_ln(
        const int* __restrict__ rowoff, const int* __restrict__ csr,
        const float* __restrict__ dinv, const unsigned* __restrict__ zbu,
        const float* __restrict__ bias, const float* __restrict__ gamma,
        const float* __restrict__ beta, float* __restrict__ out) {
    int tid = threadIdx.x;
    int w = tid >> 6, lane = tid & 63;
    int rowBase = blockIdx.x * 16 + w * 4;

    int cs[4], ce[4]; float dn[4]; unsigned selfz[4]; int v[4];
#pragma unroll
    for (int r = 0; r < 4; r++) {
        int row = rowBase + r;
        cs[r] = __builtin_amdgcn_readfirstlane(rowoff[row]);
        ce[r] = __builtin_amdgcn_readfirstlane(rowoff[row + 1]);
        dn[r] = dinv[row];
        selfz[r] = zbu[(size_t)row * 64 + lane];
    }
#pragma unroll
    for (int r = 0; r < 4; r++) {
        int m0 = ce[r] - cs[r]; if (m0 > 64) m0 = 64;
        int t0 = csr[cs[r] + lane];          // csr padded +64: in-bounds
        v[r] = (lane < m0) ? t0 : NN;        // pad -> zero sentinel row
    }

    float ax[4], ay[4];
#pragma unroll
    for (int r = 0; r < 4; r++) {
        ax[r] = __uint_as_float(selfz[r] << 16);
        ay[r] = __uint_as_float(selfz[r] & 0xFFFF0000u);
    }

    // pairwise interleave: (ra, rb) = (0,1) then (2,3). Two unconditional
    // 16-edge batches per pair cover deg<=32 (~89% of rows); sentinel loads
    // are L1-resident (+0.0f, exact).
#pragma unroll
    for (int pr = 0; pr < 2; pr++) {
        const int ra = pr * 2, rb = pr * 2 + 1;
#pragma unroll
        for (int round = 0; round < 2; round++) {
            unsigned pa[16], pb[16];
#pragma unroll
            for (int q = 0; q < 16; q++) {
                int sa = __builtin_amdgcn_readlane(v[ra], round * 16 + q);
                pa[q] = zbu[(size_t)sa * 64 + lane];
            }
#pragma unroll
            for (int q = 0; q < 16; q++) {
                int sb = __builtin_amdgcn_readlane(v[rb], round * 16 + q);
                pb[q] = zbu[(size_t)sb * 64 + lane];
            }
#pragma unroll
            for (int q = 0; q < 16; q++) {
                ax[ra] += __uint_as_float(pa[q] << 16);
                ay[ra] += __uint_as_float(pa[q] & 0xFFFF0000u);
            }
#pragma unroll
            for (int q = 0; q < 16; q++) {
                ax[rb] += __uint_as_float(pb[q] << 16);
                ay[rb] += __uint_as_float(pb[q] & 0xFFFF0000u);
            }
        }
    }

    // serial continuation: batches 2-3 (deg 33..64), then generic >64 chunks.
    float2 x[4];
#pragma unroll
    for (int r = 0; r < 4; r++) {
        int m = ce[r] - cs[r]; if (m > 64) m = 64;
        int nb = (m + 15) >> 4;
        for (int jb = 2; jb < nb; ++jb) {
            int j = jb << 4;
            unsigned p[16];
#pragma unroll
            for (int q = 0; q < 16; q++) {
                int sq = __builtin_amdgcn_readlane(v[r], j + q);
                p[q] = zbu[(size_t)sq * 64 + lane];
            }
#pragma unroll
            for (int q = 0; q < 16; q++) {
                ax[r] += __uint_as_float(p[q] << 16);
                ay[r] += __uint_as_float(p[q] & 0xFFFF0000u);
            }
        }
        int c = cs[r] + 64;
        while (c < ce[r]) {                  // absent for this graph; safety
            int m2 = ce[r] - c; if (m2 > 64) m2 = 64;
            int t2 = csr[c + lane];
            int vv = (lane < m2) ? t2 : NN;
            int nb2 = (m2 + 15) >> 4;
            for (int jb = 0; jb < nb2; ++jb) {
                int j = jb << 4;
                unsigned p[16];
#pragma unroll
                for (int q = 0; q < 16; q++) {
                    int sq = __builtin_amdgcn_readlane(vv, j + q);
                    p[q] = zbu[(size_t)sq * 64 + lane];
                }
#pragma unroll
                for (int q = 0; q < 16; q++) {
                    ax[r] += __uint_as_float(p[q] << 16);
                    ay[r] += __uint_as_float(p[q] & 0xFFFF0000u);
                }
            }
            c += 64;
        }
        x[r].x = ax[r] * dn[r];
        x[r].y = ay[r] * dn[r];
    }

    float2 bi = ((const float2*)bias)[lane];
    float2 ga = ((const float2*)gamma)[lane];
    float2 be = ((const float2*)beta)[lane];
#pragma unroll
    for (int r = 0; r < 4; r++) {
        int row = rowBase + r;
        float y0 = x[r].x + bi.x;
        float y1 = x[r].y + bi.y;
        float s = y0 + y1;
#pragma unroll
        for (int off = 32; off > 0; off >>= 1) s += __shfl_xor(s, off, 64);
        float m = s * (1.0f / 128.0f);
        float v0f = y0 - m, v1f = y1 - m;
        float vs = v0f * v0f + v1f * v1f;
#pragma unroll
        for (int off = 32; off > 0; off >>= 1) vs += __shfl_xor(vs, off, 64);
        float rstd = rsqrtf(vs * (1.0f / 128.0f) + 1e-5f);
        float2 o;
        o.x = fast_tanh(v0f * rstd * ga.x + be.x);
        o.y = fast_tanh(v1f * rstd * ga.y + be.y);
        *(float2*)&out[(size_t)row * D + lane * 2] = o;
    }
}

extern "C" void kernel_launch(void* const* d_in, const int* in_sizes, int n_in,
                              void* d_out, int out_size, void* d_ws, size_t ws_size,
                              hipStream_t stream) {
    // inputs: t, h, edge_index, batch_size, W, b, gamma, beta
    const float* h     = (const float*)d_in[1];
    const int*   ei    = (const int*)  d_in[2];
    const float* Wg    = (const float*)d_in[4];
    const float* b     = (const float*)d_in[5];
    const float* gamma = (const float*)d_in[6];
    const float* beta  = (const float*)d_in[7];
    float* out = (float*)d_out;

    // workspace layout (~44.5 MB). csr has +64-int pad (branchless chunk loads).
    char* wsb = (char*)d_ws;
    unsigned short* wpk    = (unsigned short*)(wsb);            // 32768 B
    int*            deg    = (int*)(wsb + 32768);               // NN ints
    int*            flag   = (int*)(wsb + 232768);              // 1 int
    int*            partial= (int*)(wsb + 232832);              // 64 ints
    unsigned short* rank   = (unsigned short*)(wsb + 233088);   // NE ushorts
    int*            rowoff = (int*)(wsb + 1833088);             // NN+1 ints
    float*          dinv   = (float*)(wsb + 2633152);           // NN floats
    int*            csr    = (int*)(wsb + 2833152);             // NE ints + 64 pad
    unsigned short* zb     = (unsigned short*)(wsb + 6033408);  // (NN+1)*128 ushorts
    float*          zf     = (float*)(wsb + 18833664);          // NN*128 floats

    int tailN = out_size - NN * D;                 // int-zeros tail of d_out
    int* outtail = (int*)(out + (size_t)NN * D);

    k_init       <<<64,        256, 0, stream>>>(Wg, deg, flag, wpk, zb);
    k_count_gemm <<<NROLES,    256, 0, stream>>>(h, (const uint4*)wpk, ei, deg, rank, zf, outtail, tailN);
    k_scan_scale <<<SS_BLOCKS, 256, 0, stream>>>(deg, partial, flag, rowoff, dinv, zf, zb);
    k_fill       <<<625,       320, 0, stream>>>(ei, rowoff, rank, csr);
    k_gather_ln  <<<NN / 16,   256, 0, stream>>>(rowoff, csr, dinv, (const unsigned*)zb, b, gamma, beta, out);
}

// Round 9
// 192.256 us; speedup vs baseline: 1.0133x; 1.0133x over previous
//
#include <hip/hip_runtime.h>
#include <math.h>

#define NN 50000
#define NE 800000
#define D  128
#define SCAN_CHUNK 1024
#define NSCAN 49          // ceil(NN/SCAN_CHUNK)
#define PG_BLOCKS 782     // ceil((NE/4)/256)
#define NROLES 1564       // 782 count + 782 gemm
#define SS_BLOCKS 832     // 49 scan + 783 scale (783*256 = 200448 >= NN*4)

typedef __attribute__((ext_vector_type(8))) short bf16x8;
typedef __attribute__((ext_vector_type(4))) float f32x4;

__device__ __forceinline__ unsigned short f32_to_bf16(float f) {
    unsigned u = __float_as_uint(f);
    u = u + 0x7FFFu + ((u >> 16) & 1u);   // RNE
    return (unsigned short)(u >> 16);
}

// fast tanh: 1 - 2*rcp(e^{2x}+1). Exact at saturation. |err| ~1e-6.
__device__ __forceinline__ float fast_tanh(float x) {
    float e = __expf(2.0f * x);
    return fmaf(-2.0f, __builtin_amdgcn_rcpf(e + 1.0f), 1.0f);
}

// 16 gathers forced in flight: loads + waitcnt in ONE volatile asm block.
// SGPR base + 32-bit voffset form; "=&v" keeps dsts distinct from addr regs.
#define GLD16(P, VO, BASE)                                              \
    asm volatile(                                                       \
        "global_load_dword %0, %16, %32\n\t"                            \
        "global_load_dword %1, %17, %32\n\t"                            \
        "global_load_dword %2, %18, %32\n\t"                            \
        "global_load_dword %3, %19, %32\n\t"                            \
        "global_load_dword %4, %20, %32\n\t"                            \
        "global_load_dword %5, %21, %32\n\t"                            \
        "global_load_dword %6, %22, %32\n\t"                            \
        "global_load_dword %7, %23, %32\n\t"                            \
        "global_load_dword %8, %24, %32\n\t"                            \
        "global_load_dword %9, %25, %32\n\t"                            \
        "global_load_dword %10, %26, %32\n\t"                           \
        "global_load_dword %11, %27, %32\n\t"                           \
        "global_load_dword %12, %28, %32\n\t"                           \
        "global_load_dword %13, %29, %32\n\t"                           \
        "global_load_dword %14, %30, %32\n\t"                           \
        "global_load_dword %15, %31, %32\n\t"                           \
        "s_waitcnt vmcnt(0)"                                            \
        : "=&v"(P[0]),  "=&v"(P[1]),  "=&v"(P[2]),  "=&v"(P[3]),        \
          "=&v"(P[4]),  "=&v"(P[5]),  "=&v"(P[6]),  "=&v"(P[7]),        \
          "=&v"(P[8]),  "=&v"(P[9]),  "=&v"(P[10]), "=&v"(P[11]),       \
          "=&v"(P[12]), "=&v"(P[13]), "=&v"(P[14]), "=&v"(P[15])        \
        : "v"(VO[0]),  "v"(VO[1]),  "v"(VO[2]),  "v"(VO[3]),            \
          "v"(VO[4]),  "v"(VO[5]),  "v"(VO[6]),  "v"(VO[7]),            \
          "v"(VO[8]),  "v"(VO[9]),  "v"(VO[10]), "v"(VO[11]),           \
          "v"(VO[12]), "v"(VO[13]), "v"(VO[14]), "v"(VO[15]),           \
          "s"(BASE))

// ---- K0: deg/flag zero; W bf16-frag pack (block 0); zb sentinel row --------
__global__ __launch_bounds__(256) void k_init(
        const float* __restrict__ Wg, int* __restrict__ deg,
        int* __restrict__ flag, unsigned short* __restrict__ wpk,
        unsigned short* __restrict__ zb) {
    int tid = threadIdx.x;
    int idx = blockIdx.x * 256 + tid;

    if (idx < NN / 4) ((int4*)deg)[idx] = (int4){0, 0, 0, 0};
    if (idx == NN / 4) *flag = 0;

    if (blockIdx.x == 0) {
        // frag = nt*256 + kt*64 + quad*16 + lo, elem j = k&7 (verified layout)
#pragma unroll 8
        for (int i = 0; i < 64; i++) {
            int o = i * 256 + tid;
            int j = o & 7, frag = o >> 3;
            int lo = frag & 15, quad = (frag >> 4) & 3;
            int kt = (frag >> 6) & 3, nt = frag >> 8;
            wpk[o] = f32_to_bf16(Wg[(kt * 32 + quad * 8 + j) * 128 + nt * 16 + lo]);
        }
    }
    if (blockIdx.x == 1 && tid < 64)
        ((unsigned*)(zb + (size_t)NN * D))[tid] = 0u;   // sentinel row = 0
}

// ---- K1: count-atomics blocks + GEMM blocks interleaved by parity.
// GEMM writes UNSCALED fp32 zf (no dinv dep) -> overlaps with atomics. ------
__global__ __launch_bounds__(256) void k_count_gemm(
        const float* __restrict__ h, const uint4* __restrict__ wpk4,
        const int* __restrict__ ei, int* __restrict__ deg,
        unsigned short* __restrict__ rank, float* __restrict__ zf,
        int* __restrict__ outtail, int tailN) {
    int tid = threadIdx.x;
    int bid = blockIdx.x;

    if (bid & 1) {
        int g = (bid >> 1) * 256 + tid;
        if (g < NE / 4) {
            int4 d4 = ((const int4*)(ei + NE))[g];
            ushort4 r;
            r.x = (unsigned short)atomicAdd(&deg[d4.x], 1);
            r.y = (unsigned short)atomicAdd(&deg[d4.y], 1);
            r.z = (unsigned short)atomicAdd(&deg[d4.z], 1);
            r.w = (unsigned short)atomicAdd(&deg[d4.w], 1);
            ((ushort4*)rank)[g] = r;
        }
        for (int i = g; i < tailN; i += PG_BLOCKS * 256) outtail[i] = 0;
        return;
    }

    int gid = bid >> 1;
    int w = tid >> 6, lane = tid & 63;
    int quad = lane >> 4, lo = lane & 15;
    int rowBase = gid * 64 + w * 16;
    int rowA = rowBase + lo; if (rowA > NN - 1) rowA = NN - 1;
    const float4* h4 = (const float4*)h;

    bf16x8 af[4];
#pragma unroll
    for (int kt = 0; kt < 4; kt++) {
        float4 u = h4[(size_t)rowA * 32 + kt * 8 + quad * 2];
        float4 v = h4[(size_t)rowA * 32 + kt * 8 + quad * 2 + 1];
        bf16x8 a;
        a[0] = (short)f32_to_bf16(u.x); a[1] = (short)f32_to_bf16(u.y);
        a[2] = (short)f32_to_bf16(u.z); a[3] = (short)f32_to_bf16(u.w);
        a[4] = (short)f32_to_bf16(v.x); a[5] = (short)f32_to_bf16(v.y);
        a[6] = (short)f32_to_bf16(v.z); a[7] = (short)f32_to_bf16(v.w);
        af[kt] = a;
    }

    f32x4 acc[8];
#pragma unroll
    for (int nt = 0; nt < 8; nt++) acc[nt] = (f32x4){0.f, 0.f, 0.f, 0.f};

#pragma unroll
    for (int kt = 0; kt < 4; kt++)
#pragma unroll
        for (int nt = 0; nt < 8; nt++) {
            uint4 tb = wpk4[nt * 256 + kt * 64 + lane];   // coalesced, L1-hit
            acc[nt] = __builtin_amdgcn_mfma_f32_16x16x32_bf16(
                af[kt], __builtin_bit_cast(bf16x8, tb), acc[nt], 0, 0, 0);
        }

#pragma unroll
    for (int reg = 0; reg < 4; reg++) {
        int row = rowBase + quad * 4 + reg;
        if (row < NN) {
#pragma unroll
            for (int nt = 0; nt < 8; nt++)
                zf[(size_t)row * D + nt * 16 + lo] = acc[nt][reg];
        }
    }
}

// ---- K2: scan(blocks 0-48) || zb-scale(blocks 49+). NO cross-block deps:
// scale recomputes dinv inline from deg (bit-identical). Kernel boundary
// (not an in-kernel barrier) publishes rowoff to K3 — round-5 lesson. -------
__global__ __launch_bounds__(256) void k_scan_scale(
        const int* __restrict__ deg, int* __restrict__ partial,
        int* __restrict__ flag, int* __restrict__ rowoff,
        float* __restrict__ dinv, const float* __restrict__ zf,
        unsigned short* __restrict__ zb) {
    __shared__ int wsum[4];
    int tid = threadIdx.x;
    int bid = blockIdx.x;

    if (bid < NSCAN) {
        // ---------------- scan role (proven structure) ----------------
        int lane = tid & 63, wv = tid >> 6;
        int base = bid * SCAN_CHUNK + tid * 4;
        int d[4]; int s = 0;
#pragma unroll
        for (int j = 0; j < 4; j++) {
            int i = base + j;
            d[j] = 0;
            if (i < NN) {
                d[j] = deg[i];
                s += d[j];
                dinv[i] = rsqrtf((float)d[j] + 1.0f);   // +1 self loop
            }
        }
        int v = s;
#pragma unroll
        for (int off = 1; off < 64; off <<= 1) {
            int u = __shfl_up(v, off, 64);
            if (lane >= off) v += u;
        }
        if (lane == 63) wsum[wv] = v;
        __syncthreads();
        int add = 0;
#pragma unroll
        for (int k = 0; k < 4; k++) if (k < wv) add += wsum[k];
        int inc = v + add;
        if (tid == 255) {
            atomicExch(&partial[bid], inc);
            __threadfence();
            atomicAdd(flag, 1);
            while (atomicAdd(flag, 0) < NSCAN) {}   // 49 spinners, co-resident
        }
        __syncthreads();
        int pv = (lane < NSCAN && lane < bid) ? atomicAdd(&partial[lane], 0) : 0;
#pragma unroll
        for (int off = 32; off > 0; off >>= 1) pv += __shfl_xor(pv, off, 64);
        int ex = inc - s + pv;
#pragma unroll
        for (int j = 0; j < 4; j++) {
            int i = base + j;
            if (i < NN) {
                rowoff[i] = ex;
                ex += d[j];
                if (i == NN - 1) rowoff[NN] = ex;   // sentinel = NE
            }
        }
    } else {
        // ------- scale role: zb = bf16(zf * rsqrt(deg+1)), bit-identical ----
        int g = (bid - NSCAN) * 256 + tid;
        if (g < NN * 4) {
            int row = g >> 2, seg = g & 3;
            float dn = rsqrtf((float)deg[row] + 1.0f);
            const float4* src = (const float4*)(zf + (size_t)row * D + seg * 32);
            uint4* dst = (uint4*)(zb + (size_t)row * D + seg * 32);
#pragma unroll
            for (int i = 0; i < 4; i++) {
                float4 a = src[i * 2], bb = src[i * 2 + 1];
                uint4 o;
                o.x = (unsigned)f32_to_bf16(a.x * dn) | ((unsigned)f32_to_bf16(a.y * dn) << 16);
                o.y = (unsigned)f32_to_bf16(a.z * dn) | ((unsigned)f32_to_bf16(a.w * dn) << 16);
                o.z = (unsigned)f32_to_bf16(bb.x * dn) | ((unsigned)f32_to_bf16(bb.y * dn) << 16);
                o.w = (unsigned)f32_to_bf16(bb.z * dn) | ((unsigned)f32_to_bf16(bb.w * dn) << 16);
                dst[i] = o;
            }
        }
    }
}

// ---- K3: CSR fill, plain cached loads (kernel boundary = coherence) -------
__global__ __launch_bounds__(320) void k_fill(const int* __restrict__ ei,
                                              const int* __restrict__ rowoff,
                                              const unsigned short* __restrict__ rank,
                                              int* __restrict__ csr) {
    int t = blockIdx.x * 320 + threadIdx.x;   // 625*320*4 = NE exactly
    int4 s4 = ((const int4*)ei)[t];
    int4 d4 = ((const int4*)(ei + NE))[t];
    ushort4 r4 = ((const ushort4*)rank)[t];
    csr[rowoff[d4.x] + r4.x] = s4.x;
    csr[rowoff[d4.y] + r4.y] = s4.y;
    csr[rowoff[d4.z] + r4.z] = s4.z;
    csr[rowoff[d4.w] + r4.w] = s4.w;
}

// ---- K4: gather + LN + tanh. ONE delta vs round 6: every 16-edge batch
// issues through GLD16 (asm-forced 16 loads in flight; compiler was sinking
// loads to VGPR=36 / MLP~4). Per-row summation order unchanged -> bit-id. ---
__global__ __launch_bounds__(256) void k_gather_ln(
        const int* __restrict__ rowoff, const int* __restrict__ csr,
        const float* __restrict__ dinv, const unsigned* __restrict__ zbu,
        const float* __restrict__ bias, const float* __restrict__ gamma,
        const float* __restrict__ beta, float* __restrict__ out) {
    int tid = threadIdx.x;
    int w = tid >> 6, lane = tid & 63;
    int rowBase = blockIdx.x * 16 + w * 4;
    unsigned lane4 = (unsigned)(lane << 2);

    int cs[4], ce[4]; float dn[4]; unsigned selfz[4]; int v[4];
#pragma unroll
    for (int r = 0; r < 4; r++) {
        int row = rowBase + r;
        cs[r] = __builtin_amdgcn_readfirstlane(rowoff[row]);
        ce[r] = __builtin_amdgcn_readfirstlane(rowoff[row + 1]);
        dn[r] = dinv[row];
        selfz[r] = zbu[(size_t)row * 64 + lane];
    }
#pragma unroll
    for (int r = 0; r < 4; r++) {
        int m0 = ce[r] - cs[r]; if (m0 > 64) m0 = 64;
        int t0 = csr[cs[r] + lane];          // csr padded +64: in-bounds
        v[r] = (lane < m0) ? t0 : NN;        // pad -> zero sentinel row
    }

    float ax[4], ay[4];
#pragma unroll
    for (int r = 0; r < 4; r++) {
        ax[r] = __uint_as_float(selfz[r] << 16);
        ay[r] = __uint_as_float(selfz[r] & 0xFFFF0000u);
    }

    float2 x[4];
#pragma unroll
    for (int r = 0; r < 4; r++) {
        int m = ce[r] - cs[r]; if (m > 64) m = 64;
        int nb = (m + 15) >> 4;              // uniform per row
        for (int jb = 0; jb < nb; ++jb) {
            int j = jb << 4;
            unsigned vo[16], p[16];
#pragma unroll
            for (int q = 0; q < 16; q++) {
                int sq = __builtin_amdgcn_readlane(v[r], j + q);
                vo[q] = ((unsigned)sq << 8) + lane4;   // byte offset in zb
            }
            GLD16(p, vo, zbu);
#pragma unroll
            for (int q = 0; q < 16; q++) {
                ax[r] += __uint_as_float(p[q] << 16);
                ay[r] += __uint_as_float(p[q] & 0xFFFF0000u);
            }
        }
        int c = cs[r] + 64;
        while (c < ce[r]) {                  // absent for this graph; safety
            int m2 = ce[r] - c; if (m2 > 64) m2 = 64;
            int t2 = csr[c + lane];
            int vv = (lane < m2) ? t2 : NN;
            int nb2 = (m2 + 15) >> 4;
            for (int jb = 0; jb < nb2; ++jb) {
                int j = jb << 4;
                unsigned vo[16], p[16];
#pragma unroll
                for (int q = 0; q < 16; q++) {
                    int sq = __builtin_amdgcn_readlane(vv, j + q);
                    vo[q] = ((unsigned)sq << 8) + lane4;
                }
                GLD16(p, vo, zbu);
#pragma unroll
                for (int q = 0; q < 16; q++) {
                    ax[r] += __uint_as_float(p[q] << 16);
                    ay[r] += __uint_as_float(p[q] & 0xFFFF0000u);
                }
            }
            c += 64;
        }
        x[r].x = ax[r] * dn[r];
        x[r].y = ay[r] * dn[r];
    }

    float2 bi = ((const float2*)bias)[lane];
    float2 ga = ((const float2*)gamma)[lane];
    float2 be = ((const float2*)beta)[lane];
#pragma unroll
    for (int r = 0; r < 4; r++) {
        int row = rowBase + r;
        float y0 = x[r].x + bi.x;
        float y1 = x[r].y + bi.y;
        float s = y0 + y1;
#pragma unroll
        for (int off = 32; off > 0; off >>= 1) s += __shfl_xor(s, off, 64);
        float m = s * (1.0f / 128.0f);
        float v0f = y0 - m, v1f = y1 - m;
        float vs = v0f * v0f + v1f * v1f;
#pragma unroll
        for (int off = 32; off > 0; off >>= 1) vs += __shfl_xor(vs, off, 64);
        float rstd = rsqrtf(vs * (1.0f / 128.0f) + 1e-5f);
        float2 o;
        o.x = fast_tanh(v0f * rstd * ga.x + be.x);
        o.y = fast_tanh(v1f * rstd * ga.y + be.y);
        *(float2*)&out[(size_t)row * D + lane * 2] = o;
    }
}

extern "C" void kernel_launch(void* const* d_in, const int* in_sizes, int n_in,
                              void* d_out, int out_size, void* d_ws, size_t ws_size,
                              hipStream_t stream) {
    // inputs: t, h, edge_index, batch_size, W, b, gamma, beta
    const float* h     = (const float*)d_in[1];
    const int*   ei    = (const int*)  d_in[2];
    const float* Wg    = (const float*)d_in[4];
    const float* b     = (const float*)d_in[5];
    const float* gamma = (const float*)d_in[6];
    const float* beta  = (const float*)d_in[7];
    float* out = (float*)d_out;

    // workspace layout (~44.5 MB). csr has +64-int pad (branchless chunk loads).
    char* wsb = (char*)d_ws;
    unsigned short* wpk    = (unsigned short*)(wsb);            // 32768 B
    int*            deg    = (int*)(wsb + 32768);               // NN ints
    int*            flag   = (int*)(wsb + 232768);              // 1 int
    int*            partial= (int*)(wsb + 232832);              // 64 ints
    unsigned short* rank   = (unsigned short*)(wsb + 233088);   // NE ushorts
    int*            rowoff = (int*)(wsb + 1833088);             // NN+1 ints
    float*          dinv   = (float*)(wsb + 2633152);           // NN floats
    int*            csr    = (int*)(wsb + 2833152);             // NE ints + 64 pad
    unsigned short* zb     = (unsigned short*)(wsb + 6033408);  // (NN+1)*128 ushorts
    float*          zf     = (float*)(wsb + 18833664);          // NN*128 floats

    int tailN = out_size - NN * D;                 // int-zeros tail of d_out
    int* outtail = (int*)(out + (size_t)NN * D);

    k_init       <<<64,        256, 0, stream>>>(Wg, deg, flag, wpk, zb);
    k_count_gemm <<<NROLES,    256, 0, stream>>>(h, (const uint4*)wpk, ei, deg, rank, zf, outtail, tailN);
    k_scan_scale <<<SS_BLOCKS, 256, 0, stream>>>(deg, partial, flag, rowoff, dinv, zf, zb);
    k_fill       <<<625,       320, 0, stream>>>(ei, rowoff, rank, csr);
    k_gather_ln  <<<NN / 16,   256, 0, stream>>>(rowoff, csr, dinv, (const unsigned*)zb, b, gamma, beta, out);
}

// Round 10
// 188.404 us; speedup vs baseline: 1.0341x; 1.0204x over previous
//
#include <hip/hip_runtime.h>
#include <math.h>

#define NN 50000
#define NE 800000
#define D  128
#define PG_BLOCKS 782     // ceil((NE/4)/256)
#define NROLES 1564       // 782 count + 782 gemm
#define SC_BLOCKS 782     // ceil(NN*4/256)

typedef __attribute__((ext_vector_type(8))) short bf16x8;
typedef __attribute__((ext_vector_type(4))) float f32x4;

__device__ __forceinline__ unsigned short f32_to_bf16(float f) {
    unsigned u = __float_as_uint(f);
    u = u + 0x7FFFu + ((u >> 16) & 1u);   // RNE
    return (unsigned short)(u >> 16);
}

// fast tanh: 1 - 2*rcp(e^{2x}+1). Exact at saturation. |err| ~1e-6.
__device__ __forceinline__ float fast_tanh(float x) {
    float e = __expf(2.0f * x);
    return fmaf(-2.0f, __builtin_amdgcn_rcpf(e + 1.0f), 1.0f);
}

// 16 gathers forced in flight: loads + waitcnt in ONE volatile asm block.
// SGPR base + 32-bit voffset form; "=&v" keeps dsts distinct from addr regs.
#define GLD16(P, VO, BASE)                                              \
    asm volatile(                                                       \
        "global_load_dword %0, %16, %32\n\t"                            \
        "global_load_dword %1, %17, %32\n\t"                            \
        "global_load_dword %2, %18, %32\n\t"                            \
        "global_load_dword %3, %19, %32\n\t"                            \
        "global_load_dword %4, %20, %32\n\t"                            \
        "global_load_dword %5, %21, %32\n\t"                            \
        "global_load_dword %6, %22, %32\n\t"                            \
        "global_load_dword %7, %23, %32\n\t"                            \
        "global_load_dword %8, %24, %32\n\t"                            \
        "global_load_dword %9, %25, %32\n\t"                            \
        "global_load_dword %10, %26, %32\n\t"                           \
        "global_load_dword %11, %27, %32\n\t"                           \
        "global_load_dword %12, %28, %32\n\t"                           \
        "global_load_dword %13, %29, %32\n\t"                           \
        "global_load_dword %14, %30, %32\n\t"                           \
        "global_load_dword %15, %31, %32\n\t"                           \
        "s_waitcnt vmcnt(0)"                                            \
        : "=&v"(P[0]),  "=&v"(P[1]),  "=&v"(P[2]),  "=&v"(P[3]),        \
          "=&v"(P[4]),  "=&v"(P[5]),  "=&v"(P[6]),  "=&v"(P[7]),        \
          "=&v"(P[8]),  "=&v"(P[9]),  "=&v"(P[10]), "=&v"(P[11]),       \
          "=&v"(P[12]), "=&v"(P[13]), "=&v"(P[14]), "=&v"(P[15])        \
        : "v"(VO[0]),  "v"(VO[1]),  "v"(VO[2]),  "v"(VO[3]),            \
          "v"(VO[4]),  "v"(VO[5]),  "v"(VO[6]),  "v"(VO[7]),            \
          "v"(VO[8]),  "v"(VO[9]),  "v"(VO[10]), "v"(VO[11]),           \
          "v"(VO[12]), "v"(VO[13]), "v"(VO[14]), "v"(VO[15]),           \
          "s"(BASE))

// ---- K0: deg zero; W bf16-frag pack (block 0); zb sentinel row ------------
__global__ __launch_bounds__(256) void k_init(
        const float* __restrict__ Wg, int* __restrict__ deg,
        unsigned short* __restrict__ wpk, unsigned short* __restrict__ zb) {
    int tid = threadIdx.x;
    int idx = blockIdx.x * 256 + tid;

    if (idx < NN / 4) ((int4*)deg)[idx] = (int4){0, 0, 0, 0};

    if (blockIdx.x == 0) {
        // frag = nt*256 + kt*64 + quad*16 + lo, elem j = k&7 (verified layout)
#pragma unroll 8
        for (int i = 0; i < 64; i++) {
            int o = i * 256 + tid;
            int j = o & 7, frag = o >> 3;
            int lo = frag & 15, quad = (frag >> 4) & 3;
            int kt = (frag >> 6) & 3, nt = frag >> 8;
            wpk[o] = f32_to_bf16(Wg[(kt * 32 + quad * 8 + j) * 128 + nt * 16 + lo]);
        }
    }
    if (blockIdx.x == 1 && tid < 64)
        ((unsigned*)(zb + (size_t)NN * D))[tid] = 0u;   // sentinel row = 0
}

// ---- K1: count role writes ELL slots DIRECTLY from the atomic's return
// (csr fill kernel eliminated); GEMM role unchanged (zf = hW, unscaled). ----
__global__ __launch_bounds__(256) void k_count_gemm(
        const float* __restrict__ h, const uint4* __restrict__ wpk4,
        const int* __restrict__ ei, int* __restrict__ deg,
        int* __restrict__ ell, float* __restrict__ zf,
        int* __restrict__ outtail, int tailN) {
    int tid = threadIdx.x;
    int bid = blockIdx.x;

    if (bid & 1) {
        int g = (bid >> 1) * 256 + tid;
        if (g < NE / 4) {
            int4 s4 = ((const int4*)ei)[g];
            int4 d4 = ((const int4*)(ei + NE))[g];
            int rx = atomicAdd(&deg[d4.x], 1);
            int ry = atomicAdd(&deg[d4.y], 1);
            int rz = atomicAdd(&deg[d4.z], 1);
            int rw = atomicAdd(&deg[d4.w], 1);
            // deg>64 impossible for this graph (Binomial mean 16, 12 sigma);
            // guard keeps OOB writes out anyway.
            if (rx < 64) ell[(size_t)d4.x * 64 + rx] = s4.x;
            if (ry < 64) ell[(size_t)d4.y * 64 + ry] = s4.y;
            if (rz < 64) ell[(size_t)d4.z * 64 + rz] = s4.z;
            if (rw < 64) ell[(size_t)d4.w * 64 + rw] = s4.w;
        }
        for (int i = g; i < tailN; i += PG_BLOCKS * 256) outtail[i] = 0;
        return;
    }

    int gid = bid >> 1;
    int w = tid >> 6, lane = tid & 63;
    int quad = lane >> 4, lo = lane & 15;
    int rowBase = gid * 64 + w * 16;
    int rowA = rowBase + lo; if (rowA > NN - 1) rowA = NN - 1;
    const float4* h4 = (const float4*)h;

    bf16x8 af[4];
#pragma unroll
    for (int kt = 0; kt < 4; kt++) {
        float4 u = h4[(size_t)rowA * 32 + kt * 8 + quad * 2];
        float4 v = h4[(size_t)rowA * 32 + kt * 8 + quad * 2 + 1];
        bf16x8 a;
        a[0] = (short)f32_to_bf16(u.x); a[1] = (short)f32_to_bf16(u.y);
        a[2] = (short)f32_to_bf16(u.z); a[3] = (short)f32_to_bf16(u.w);
        a[4] = (short)f32_to_bf16(v.x); a[5] = (short)f32_to_bf16(v.y);
        a[6] = (short)f32_to_bf16(v.z); a[7] = (short)f32_to_bf16(v.w);
        af[kt] = a;
    }

    f32x4 acc[8];
#pragma unroll
    for (int nt = 0; nt < 8; nt++) acc[nt] = (f32x4){0.f, 0.f, 0.f, 0.f};

#pragma unroll
    for (int kt = 0; kt < 4; kt++)
#pragma unroll
        for (int nt = 0; nt < 8; nt++) {
            uint4 tb = wpk4[nt * 256 + kt * 64 + lane];   // coalesced, L1-hit
            acc[nt] = __builtin_amdgcn_mfma_f32_16x16x32_bf16(
                af[kt], __builtin_bit_cast(bf16x8, tb), acc[nt], 0, 0, 0);
        }

#pragma unroll
    for (int reg = 0; reg < 4; reg++) {
        int row = rowBase + quad * 4 + reg;
        if (row < NN) {
#pragma unroll
            for (int nt = 0; nt < 8; nt++)
                zf[(size_t)row * D + nt * 16 + lo] = acc[nt][reg];
        }
    }
}

// ---- K2: pure streaming scale: zb = bf16(zf * rsqrt(deg+1)). No scan, no
// spin, no role split — the ELL rework removed rowoff from the pipeline. ----
__global__ __launch_bounds__(256) void k_scale(
        const int* __restrict__ deg, const float* __restrict__ zf,
        unsigned short* __restrict__ zb) {
    int g = blockIdx.x * 256 + threadIdx.x;
    if (g < NN * 4) {
        int row = g >> 2, seg = g & 3;
        float dn = rsqrtf((float)deg[row] + 1.0f);   // +1 self loop
        const float4* src = (const float4*)(zf + (size_t)row * D + seg * 32);
        uint4* dst = (uint4*)(zb + (size_t)row * D + seg * 32);
#pragma unroll
        for (int i = 0; i < 4; i++) {
            float4 a = src[i * 2], bb = src[i * 2 + 1];
            uint4 o;
            o.x = (unsigned)f32_to_bf16(a.x * dn) | ((unsigned)f32_to_bf16(a.y * dn) << 16);
            o.y = (unsigned)f32_to_bf16(a.z * dn) | ((unsigned)f32_to_bf16(a.w * dn) << 16);
            o.z = (unsigned)f32_to_bf16(bb.x * dn) | ((unsigned)f32_to_bf16(bb.y * dn) << 16);
            o.w = (unsigned)f32_to_bf16(bb.z * dn) | ((unsigned)f32_to_bf16(bb.w * dn) << 16);
            dst[i] = o;
        }
    }
}

// ---- K3: gather + LN + tanh over ELL rows. deg/dinv recomputed inline
// (bit-identical rsqrtf input); slot-order summation unchanged -> bit-id. ---
__global__ __launch_bounds__(256) void k_gather_ln(
        const int* __restrict__ deg, const int* __restrict__ ell,
        const unsigned* __restrict__ zbu,
        const float* __restrict__ bias, const float* __restrict__ gamma,
        const float* __restrict__ beta, float* __restrict__ out) {
    int tid = threadIdx.x;
    int w = tid >> 6, lane = tid & 63;
    int rowBase = blockIdx.x * 16 + w * 4;
    unsigned lane4 = (unsigned)(lane << 2);

    int m0[4]; float dn[4]; unsigned selfz[4]; int v[4];
#pragma unroll
    for (int r = 0; r < 4; r++) {
        int row = rowBase + r;
        int dg = __builtin_amdgcn_readfirstlane(deg[row]);
        dn[r] = rsqrtf((float)dg + 1.0f);
        m0[r] = (dg > 64) ? 64 : dg;
        selfz[r] = zbu[(size_t)row * 64 + lane];
        int t0 = ell[(size_t)row * 64 + lane];   // coalesced 256B row
        v[r] = (lane < m0[r]) ? t0 : NN;         // pad -> zero sentinel row
    }

    float ax[4], ay[4];
#pragma unroll
    for (int r = 0; r < 4; r++) {
        ax[r] = __uint_as_float(selfz[r] << 16);
        ay[r] = __uint_as_float(selfz[r] & 0xFFFF0000u);
    }

    float2 x[4];
#pragma unroll
    for (int r = 0; r < 4; r++) {
        int nb = (m0[r] + 15) >> 4;              // uniform per row
        for (int jb = 0; jb < nb; ++jb) {
            int j = jb << 4;
            unsigned vo[16], p[16];
#pragma unroll
            for (int q = 0; q < 16; q++) {
                int sq = __builtin_amdgcn_readlane(v[r], j + q);
                vo[q] = ((unsigned)sq << 8) + lane4;   // byte offset in zb
            }
            GLD16(p, vo, zbu);
#pragma unroll
            for (int q = 0; q < 16; q++) {
                ax[r] += __uint_as_float(p[q] << 16);
                ay[r] += __uint_as_float(p[q] & 0xFFFF0000u);
            }
        }
        x[r].x = ax[r] * dn[r];
        x[r].y = ay[r] * dn[r];
    }

    float2 bi = ((const float2*)bias)[lane];
    float2 ga = ((const float2*)gamma)[lane];
    float2 be = ((const float2*)beta)[lane];
#pragma unroll
    for (int r = 0; r < 4; r++) {
        int row = rowBase + r;
        float y0 = x[r].x + bi.x;
        float y1 = x[r].y + bi.y;
        float s = y0 + y1;
#pragma unroll
        for (int off = 32; off > 0; off >>= 1) s += __shfl_xor(s, off, 64);
        float m = s * (1.0f / 128.0f);
        float v0f = y0 - m, v1f = y1 - m;
        float vs = v0f * v0f + v1f * v1f;
#pragma unroll
        for (int off = 32; off > 0; off >>= 1) vs += __shfl_xor(vs, off, 64);
        float rstd = rsqrtf(vs * (1.0f / 128.0f) + 1e-5f);
        float2 o;
        o.x = fast_tanh(v0f * rstd * ga.x + be.x);
        o.y = fast_tanh(v1f * rstd * ga.y + be.y);
        *(float2*)&out[(size_t)row * D + lane * 2] = o;
    }
}

extern "C" void kernel_launch(void* const* d_in, const int* in_sizes, int n_in,
                              void* d_out, int out_size, void* d_ws, size_t ws_size,
                              hipStream_t stream) {
    // inputs: t, h, edge_index, batch_size, W, b, gamma, beta
    const float* h     = (const float*)d_in[1];
    const int*   ei    = (const int*)  d_in[2];
    const float* Wg    = (const float*)d_in[4];
    const float* b     = (const float*)d_in[5];
    const float* gamma = (const float*)d_in[6];
    const float* beta  = (const float*)d_in[7];
    float* out = (float*)d_out;

    // workspace layout (~51.4 MB): wpk | deg | ell | zb | zf
    char* wsb = (char*)d_ws;
    unsigned short* wpk = (unsigned short*)(wsb);            // 32768 B
    int*            deg = (int*)(wsb + 32768);               // NN ints -> 232768
    int*            ell = (int*)(wsb + 232768);              // NN*64 ints -> 13032768
    unsigned short* zb  = (unsigned short*)(wsb + 13032768); // (NN+1)*128 ushorts -> 25833024
    float*          zf  = (float*)(wsb + 25833024);          // NN*128 floats -> 51433024

    int tailN = out_size - NN * D;                 // int-zeros tail of d_out
    int* outtail = (int*)(out + (size_t)NN * D);

    k_init       <<<64,        256, 0, stream>>>(Wg, deg, wpk, zb);
    k_count_gemm <<<NROLES,    256, 0, stream>>>(h, (const uint4*)wpk, ei, deg, ell, zf, outtail, tailN);
    k_scale      <<<SC_BLOCKS, 256, 0, stream>>>(deg, zf, zb);
    k_gather_ln  <<<NN / 16,   256, 0, stream>>>(deg, ell, (const unsigned*)zb, b, gamma, beta, out);
}